// Round 1
// baseline (562.272 us; speedup 1.0000x reference)
//
#include <hip/hip_runtime.h>

#define NB 256   // batches
#define ND 256   // d
#define NN 1024  // n

typedef _Float16 f16_t;
typedef _Float16 f16x8 __attribute__((ext_vector_type(8)));
typedef float    f32x4 __attribute__((ext_vector_type(4)));
typedef float    f32x16 __attribute__((ext_vector_type(16)));

// ---------------------------------------------------------------------------
// Kernel 1: per-batch Gram matrix G = A A^T, A = x[b] (256 x 1024 row-major).
// fp32 -> fp16 inputs, fp32 MFMA accumulate, G stored fp16 row-major [256][256].
// One 512-thread block per batch; 8 waves, each computing a 64x128 slab of G
// with 32x32x16 f16 MFMA. Double-buffered LDS staging with XOR-swizzled 16B
// chunks (conflict-free b128 reads/writes).
// ---------------------------------------------------------------------------
__global__ __launch_bounds__(512, 2) void k1_gram(const float* __restrict__ x,
                                                  f16_t* __restrict__ g)
{
    __shared__ __align__(16) f16_t sbuf[2][256 * 64];   // 64 KB, chunk-swizzled

    const int t = threadIdx.x;
    const int b = blockIdx.x;
    const float* xb = x + (size_t)b * ND * NN;

    // ---- loader mapping: thread t covers chunk c8 (8 floats) of 4 rows
    const int c8    = t & 7;       // k-chunk within 64-col slice
    const int rbase = t >> 3;      // 0..63

    f32x4 pf[8];

    auto issue = [&](int kc) {
        const float* base = xb + (size_t)kc * 64 + c8 * 8;
        #pragma unroll
        for (int kk = 0; kk < 4; ++kk) {
            const float* p = base + (size_t)(rbase + 64 * kk) * NN;
            pf[2 * kk]     = *(const f32x4*)p;
            pf[2 * kk + 1] = *(const f32x4*)(p + 4);
        }
    };
    auto commit = [&](int buf) {
        #pragma unroll
        for (int kk = 0; kk < 4; ++kk) {
            const int row = rbase + 64 * kk;
            f16x8 h;
            #pragma unroll
            for (int j = 0; j < 4; ++j) {
                h[j]     = (f16_t)pf[2 * kk][j];
                h[4 + j] = (f16_t)pf[2 * kk + 1][j];
            }
            *(f16x8*)&sbuf[buf][row * 64 + ((c8 ^ (row & 7)) << 3)] = h;
        }
    };

    // ---- MFMA mapping
    const int w     = t >> 6;        // wave 0..7
    const int lane  = t & 63;
    const int mbase = (w & 3) * 64;  // 4 row-slabs of 64
    const int nbase = (w >> 2) * 128;// 2 col-slabs of 128
    const int fr    = lane & 31;
    const int half  = lane >> 5;

    f32x16 acc[2][4] = {};

    issue(0);
    commit(0);

    for (int kc = 0; kc < 16; ++kc) {
        __syncthreads();
        if (kc < 15) issue(kc + 1);
        const f16_t* sb = sbuf[kc & 1];
        #pragma unroll
        for (int ks = 0; ks < 4; ++ks) {
            const int ch = ks * 2 + half;     // 16B chunk index: k = ks*16 + half*8 + j
            f16x8 bf[4];
            #pragma unroll
            for (int nb = 0; nb < 4; ++nb) {
                const int row = nbase + nb * 32 + fr;
                bf[nb] = *(const f16x8*)&sb[row * 64 + ((ch ^ (row & 7)) << 3)];
            }
            #pragma unroll
            for (int mb = 0; mb < 2; ++mb) {
                const int row = mbase + mb * 32 + fr;
                const f16x8 af = *(const f16x8*)&sb[row * 64 + ((ch ^ (row & 7)) << 3)];
                #pragma unroll
                for (int nb = 0; nb < 4; ++nb)
                    acc[mb][nb] = __builtin_amdgcn_mfma_f32_32x32x16_f16(
                        af, bf[nb], acc[mb][nb], 0, 0, 0);
            }
        }
        if (kc < 15) commit((kc + 1) & 1);
    }

    // ---- epilogue: fp32 acc -> fp16 G
    // C/D layout (32x32): col = lane&31, row = (reg&3) + 8*(reg>>2) + 4*(lane>>5)
    f16_t* gb = g + (size_t)b * ND * ND;
    #pragma unroll
    for (int mb = 0; mb < 2; ++mb)
        #pragma unroll
        for (int nb = 0; nb < 4; ++nb) {
            const int gcol = nbase + nb * 32 + fr;
            #pragma unroll
            for (int r = 0; r < 16; ++r) {
                const int grow = mbase + mb * 32 + (r & 3) + 8 * (r >> 2) + 4 * half;
                gb[grow * ND + gcol] = (f16_t)acc[mb][nb][r];
            }
        }
}

// ---------------------------------------------------------------------------
// Kernel 2: per-batch power iteration on G (implicit deflation G' = G - s1^2 v1 v1^T).
// 256 threads = one per row of G. G rows read straight from global (L1/L2 resident).
// Writes per-batch vectors {va, vb, v1, v2} and scalar params to workspace.
// ---------------------------------------------------------------------------
__global__ __launch_bounds__(256, 1) void k2_power(const f16_t* __restrict__ g,
                                                   const float* __restrict__ wvec,
                                                   float* __restrict__ vecs,  // [NB][4][ND]
                                                   float* __restrict__ pars)  // [NB][8]
{
    __shared__ float sv[ND];
    __shared__ float sv1[ND];
    __shared__ float sred[4];

    const int t = threadIdx.x;
    const int b = blockIdx.x;
    const f16_t* gr = g + (size_t)b * ND * ND + (size_t)t * ND;

    auto reduce = [&](float val) -> float {
        #pragma unroll
        for (int off = 32; off > 0; off >>= 1) val += __shfl_xor(val, off, 64);
        __syncthreads();                 // protect sred from previous reduction's readers
        if ((t & 63) == 0) sred[t >> 6] = val;
        __syncthreads();
        return sred[0] + sred[1] + sred[2] + sred[3];
    };

    auto rowdot = [&](void) -> float {   // (G v)[t]
        float acc = 0.f;
        #pragma unroll
        for (int c = 0; c < ND; c += 8) {
            const f16x8 g8 = *(const f16x8*)&gr[c];
            #pragma unroll
            for (int j = 0; j < 8; ++j) acc += (float)g8[j] * sv[c + j];
        }
        return acc;
    };

    // ---------------- component 1 ----------------
    sv[t] = wvec[t];
    __syncthreads();

    float s1 = 0.f, n1 = 1.f;
    for (int it = 0; it < 3; ++it) {
        const float p  = rowdot();
        const float pp = reduce(p * p);
        const float nrm = fmaxf(sqrtf(pp), 1e-12f);
        if (it == 2) {
            const float pv = reduce(p * sv[t]);   // v2^T G v2
            n1 = sqrtf(pv);
            s1 = sqrtf(pp) / n1;
            vecs[((size_t)b * 4 + 0) * ND + t] = sv[t];     // va = v2
            vecs[((size_t)b * 4 + 2) * ND + t] = p / nrm;   // v1 = v3
            sv1[t] = p / nrm;
        }
        sv[t] = p / nrm;
        __syncthreads();
    }

    // ---------------- component 2 (deflated) ----------------
    sv[t] = wvec[t];
    __syncthreads();

    float s2 = 0.f, n2 = 1.f, d1b = 0.f;
    const float s1sq = s1 * s1;
    for (int it = 0; it < 3; ++it) {
        const float d1 = reduce(sv1[t] * sv[t]);            // v1 . v
        const float p  = rowdot() - s1sq * d1 * sv1[t];     // G' v
        const float pp = reduce(p * p);
        const float nrm = fmaxf(sqrtf(pp), 1e-12f);
        if (it == 2) {
            const float pv = reduce(p * sv[t]);             // v2'^T G' v2'
            n2  = sqrtf(pv);
            s2  = sqrtf(pp) / n2;
            d1b = d1;
            vecs[((size_t)b * 4 + 1) * ND + t] = sv[t];     // vb = v2'
            vecs[((size_t)b * 4 + 3) * ND + t] = p / nrm;   // v2 = v3'
        }
        sv[t] = p / nrm;
        __syncthreads();
    }

    if (t == 0) {
        const float r = 1.f / (sqrtf(s2) + 1e-5f);
        float* pb = pars + b * 8;
        pb[0] = 1.f / n1;            // inv_n1
        pb[1] = 1.f / n2;            // inv_n2
        pb[2] = s1 * d1b / n2;       // k21
        pb[3] = r;
        pb[4] = sqrtf(s1) - s1 * r;  // c1
        pb[5] = sqrtf(s2) - s2 * r;  // c2
        pb[6] = s1;
        pb[7] = s2;
    }
}

// ---------------------------------------------------------------------------
// Kernel 3: fused output pass. y = X*r + (c1*u1) v1^T + (c2*u2) v2^T.
// Grid: 256 batches x 16 column-tiles of 64. Each thread holds 16 float4 of X
// in registers, builds column-dot partials for u1/u2, LDS-reduces, transforms
// registers in place and stores. One read + one write of the 256 MB tensor.
// ---------------------------------------------------------------------------
__global__ __launch_bounds__(256, 2) void k3_out(const float* __restrict__ x,
                                                 const float* __restrict__ vecs,
                                                 const float* __restrict__ pars,
                                                 float* __restrict__ y)
{
    __shared__ float sva[ND], svb[ND], sv1[ND], sv2[ND];
    __shared__ float spr1[16][64], spr2[16][64];
    __shared__ float sg1[64], sg2[64];
    __shared__ float spar[8];

    const int t  = threadIdx.x;
    const int b  = blockIdx.x >> 4;
    const int n0 = (blockIdx.x & 15) * 64;

    {
        const float* vb = vecs + (size_t)b * 4 * ND;
        sva[t] = vb[t];
        svb[t] = vb[ND + t];
        sv1[t] = vb[2 * ND + t];
        sv2[t] = vb[3 * ND + t];
        if (t < 8) spar[t] = pars[b * 8 + t];
    }

    const int c4 = t & 15;     // float4 column group within tile
    const int rg = t >> 4;     // row group 0..15
    const float* xb = x + (size_t)b * ND * NN + n0 + c4 * 4;

    f32x4 xr[16];
    #pragma unroll
    for (int k = 0; k < 16; ++k)
        xr[k] = *(const f32x4*)(xb + (size_t)(rg + 16 * k) * NN);

    __syncthreads();

    // column-dot partials: a1 = X^T va, a2 = X^T vb (this tile's columns)
    f32x4 a1 = {0.f, 0.f, 0.f, 0.f}, a2 = {0.f, 0.f, 0.f, 0.f};
    #pragma unroll
    for (int k = 0; k < 16; ++k) {
        const int row = rg + 16 * k;
        a1 += xr[k] * sva[row];
        a2 += xr[k] * svb[row];
    }
    *(f32x4*)&spr1[rg][c4 * 4] = a1;
    *(f32x4*)&spr2[rg][c4 * 4] = a2;
    __syncthreads();

    if (t < 64) {
        float u1 = 0.f, u2 = 0.f;
        #pragma unroll
        for (int g2 = 0; g2 < 16; ++g2) { u1 += spr1[g2][t]; u2 += spr2[g2][t]; }
        const float uu1 = u1 * spar[0];                 // a1 / n1
        const float uu2 = u2 * spar[1] - spar[2] * uu1; // a2/n2 - k21*u1
        sg1[t] = spar[4] * uu1;                         // c1*u1
        sg2[t] = spar[5] * uu2;                         // c2*u2
    }
    __syncthreads();

    const float rr = spar[3];
    const f32x4 g1 = *(const f32x4*)&sg1[c4 * 4];
    const f32x4 g2 = *(const f32x4*)&sg2[c4 * 4];
    float* yb = y + (size_t)b * ND * NN + n0 + c4 * 4;
    #pragma unroll
    for (int k = 0; k < 16; ++k) {
        const int row = rg + 16 * k;
        const f32x4 o = xr[k] * rr + g1 * sv1[row] + g2 * sv2[row];
        *(f32x4*)(yb + (size_t)row * NN) = o;
    }
}

// ---------------------------------------------------------------------------
extern "C" void kernel_launch(void* const* d_in, const int* in_sizes, int n_in,
                              void* d_out, int out_size, void* d_ws, size_t ws_size,
                              hipStream_t stream)
{
    const float* x = (const float*)d_in[0];
    const float* w = (const float*)d_in[1];
    float* out = (float*)d_out;

    // fp16 G (32 MB) staged in the first part of d_out (256 MB); k3 overwrites it
    // only after k2 has consumed it (stream-ordered).
    f16_t* G = (f16_t*)d_out;

    // small per-batch results in workspace (~1.03 MB)
    float* vecs = (float*)d_ws;                  // [NB][4][ND]
    float* pars = vecs + (size_t)NB * 4 * ND;    // [NB][8]

    k1_gram<<<dim3(NB), dim3(512), 0, stream>>>(x, G);
    k2_power<<<dim3(NB), dim3(ND), 0, stream>>>(G, w, vecs, pars);
    k3_out<<<dim3(NB * 16), dim3(256), 0, stream>>>(x, vecs, pars, out);
}

// Round 2
// 545.695 us; speedup vs baseline: 1.0304x; 1.0304x over previous
//
#include <hip/hip_runtime.h>

#define NB 256   // batches
#define ND 256   // d
#define NN 1024  // n

typedef _Float16 f16_t;
typedef _Float16 f16x8 __attribute__((ext_vector_type(8)));
typedef float    f32x4 __attribute__((ext_vector_type(4)));
typedef float    f32x16 __attribute__((ext_vector_type(16)));

// ---------------------------------------------------------------------------
// Kernel 1: per-batch Gram matrix G = A A^T, A = x[b] (256 x 1024 row-major).
// fp32 -> fp16 inputs, fp32 MFMA accumulate, G stored fp16 row-major [256][256].
// One 512-thread block per batch; 8 waves, each computing a 64x128 slab of G
// with 32x32x16 f16 MFMA. Double-buffered LDS staging with XOR-swizzled 16B
// chunks (conflict-free b128 reads/writes).
// ---------------------------------------------------------------------------
__global__ __launch_bounds__(512, 2) void k1_gram(const float* __restrict__ x,
                                                  f16_t* __restrict__ g)
{
    __shared__ __align__(16) f16_t sbuf[2][256 * 64];   // 64 KB, chunk-swizzled

    const int t = threadIdx.x;
    const int b = blockIdx.x;
    const float* xb = x + (size_t)b * ND * NN;

    // ---- loader mapping: thread t covers chunk c8 (8 floats) of 4 rows
    const int c8    = t & 7;       // k-chunk within 64-col slice
    const int rbase = t >> 3;      // 0..63

    f32x4 pf[8];

    auto issue = [&](int kc) {
        const float* base = xb + (size_t)kc * 64 + c8 * 8;
        #pragma unroll
        for (int kk = 0; kk < 4; ++kk) {
            const float* p = base + (size_t)(rbase + 64 * kk) * NN;
            pf[2 * kk]     = *(const f32x4*)p;
            pf[2 * kk + 1] = *(const f32x4*)(p + 4);
        }
    };
    auto commit = [&](int buf) {
        #pragma unroll
        for (int kk = 0; kk < 4; ++kk) {
            const int row = rbase + 64 * kk;
            f16x8 h;
            #pragma unroll
            for (int j = 0; j < 4; ++j) {
                h[j]     = (f16_t)pf[2 * kk][j];
                h[4 + j] = (f16_t)pf[2 * kk + 1][j];
            }
            *(f16x8*)&sbuf[buf][row * 64 + ((c8 ^ (row & 7)) << 3)] = h;
        }
    };

    // ---- MFMA mapping
    const int w     = t >> 6;        // wave 0..7
    const int lane  = t & 63;
    const int mbase = (w & 3) * 64;  // 4 row-slabs of 64
    const int nbase = (w >> 2) * 128;// 2 col-slabs of 128
    const int fr    = lane & 31;
    const int half  = lane >> 5;

    f32x16 acc[2][4] = {};

    issue(0);
    commit(0);

    for (int kc = 0; kc < 16; ++kc) {
        __syncthreads();
        if (kc < 15) issue(kc + 1);
        const f16_t* sb = sbuf[kc & 1];
        #pragma unroll
        for (int ks = 0; ks < 4; ++ks) {
            const int ch = ks * 2 + half;     // 16B chunk index: k = ks*16 + half*8 + j
            f16x8 bf[4];
            #pragma unroll
            for (int nb = 0; nb < 4; ++nb) {
                const int row = nbase + nb * 32 + fr;
                bf[nb] = *(const f16x8*)&sb[row * 64 + ((ch ^ (row & 7)) << 3)];
            }
            #pragma unroll
            for (int mb = 0; mb < 2; ++mb) {
                const int row = mbase + mb * 32 + fr;
                const f16x8 af = *(const f16x8*)&sb[row * 64 + ((ch ^ (row & 7)) << 3)];
                #pragma unroll
                for (int nb = 0; nb < 4; ++nb)
                    acc[mb][nb] = __builtin_amdgcn_mfma_f32_32x32x16_f16(
                        af, bf[nb], acc[mb][nb], 0, 0, 0);
            }
        }
        if (kc < 15) commit((kc + 1) & 1);
    }

    // ---- epilogue: fp32 acc -> fp16 G
    // C/D layout (32x32): col = lane&31, row = (reg&3) + 8*(reg>>2) + 4*(lane>>5)
    f16_t* gb = g + (size_t)b * ND * ND;
    #pragma unroll
    for (int mb = 0; mb < 2; ++mb)
        #pragma unroll
        for (int nb = 0; nb < 4; ++nb) {
            const int gcol = nbase + nb * 32 + fr;
            #pragma unroll
            for (int r = 0; r < 16; ++r) {
                const int grow = mbase + mb * 32 + (r & 3) + 8 * (r >> 2) + 4 * half;
                gb[grow * ND + gcol] = (f16_t)acc[mb][nb][r];
            }
        }
}

// ---------------------------------------------------------------------------
// Kernel 2 (REWRITTEN): per-batch power iteration with REGISTER-RESIDENT G.
// 512 threads: thread (r = t>>1, h = t&1) holds 128 fp16 of G row r (half h)
// in 64 VGPRs, loaded ONCE coalesced. All 6 matvecs run from registers; the
// lane pair combines half-row dots via shfl_xor(1). Row quantities are
// duplicated across the pair -> block reductions carry a 0.5 factor.
// Implicit deflation G' = G - s1^2 v1 v1^T.
// ---------------------------------------------------------------------------
__global__ __launch_bounds__(512, 1) void k2_power(const f16_t* __restrict__ g,
                                                   const float* __restrict__ wvec,
                                                   float* __restrict__ vecs,  // [NB][4][ND]
                                                   float* __restrict__ pars)  // [NB][8]
{
    __shared__ float sv[ND];
    __shared__ float sv1[ND];
    __shared__ float sred[8];

    const int t = threadIdx.x;
    const int b = blockIdx.x;
    const int r = t >> 1;      // G row
    const int h = t & 1;       // column half (128 cols)

    // ---- load my half-row of G into registers (once)
    const f16_t* gr = g + (size_t)b * ND * ND + (size_t)r * ND + h * 128;
    f16x8 g8[16];
    #pragma unroll
    for (int i = 0; i < 16; ++i) g8[i] = *(const f16x8*)(gr + i * 8);

    auto reduce = [&](float val) -> float {
        #pragma unroll
        for (int off = 32; off > 0; off >>= 1) val += __shfl_xor(val, off, 64);
        __syncthreads();                 // protect sred from previous readers
        if ((t & 63) == 0) sred[t >> 6] = val;
        __syncthreads();
        float s = 0.f;
        #pragma unroll
        for (int i = 0; i < 8; ++i) s += sred[i];
        return s;
    };

    auto rowdot = [&](void) -> float {   // full (G v)[r], duplicated in lane pair
        float acc = 0.f;
        const float* svh = sv + h * 128;
        #pragma unroll
        for (int i = 0; i < 16; ++i) {
            const f32x4 va = *(const f32x4*)&svh[i * 8];
            const f32x4 vb = *(const f32x4*)&svh[i * 8 + 4];
            #pragma unroll
            for (int j = 0; j < 4; ++j) {
                acc += (float)g8[i][j]     * va[j];
                acc += (float)g8[i][4 + j] * vb[j];
            }
        }
        acc += __shfl_xor(acc, 1, 64);   // combine halves: lanes t, t^1 adjacent
        return acc;
    };

    // ---------------- component 1 ----------------
    if (h == 0) sv[r] = wvec[r];
    __syncthreads();

    float s1 = 0.f, n1 = 1.f;
    for (int it = 0; it < 3; ++it) {
        const float p  = rowdot();
        const float pp = reduce(0.5f * p * p);          // rows duplicated x2
        const float nrm = fmaxf(sqrtf(pp), 1e-12f);
        if (it == 2) {
            const float pv = reduce(0.5f * p * sv[r]);  // v2^T G v2
            n1 = sqrtf(pv);
            s1 = sqrtf(pp) / n1;
            if (h == 0) {
                vecs[((size_t)b * 4 + 0) * ND + r] = sv[r];     // va = v2
                vecs[((size_t)b * 4 + 2) * ND + r] = p / nrm;   // v1 = v3
            }
            sv1[r] = p / nrm;   // duplicated write, same value
        }
        if (h == 0) sv[r] = p / nrm;
        __syncthreads();
    }

    // ---------------- component 2 (deflated) ----------------
    if (h == 0) sv[r] = wvec[r];
    __syncthreads();

    float s2 = 0.f, n2 = 1.f, d1b = 0.f;
    const float s1sq = s1 * s1;
    for (int it = 0; it < 3; ++it) {
        const float d1 = reduce(0.5f * sv1[r] * sv[r]);     // v1 . v
        const float p  = rowdot() - s1sq * d1 * sv1[r];     // G' v
        const float pp = reduce(0.5f * p * p);
        const float nrm = fmaxf(sqrtf(pp), 1e-12f);
        if (it == 2) {
            const float pv = reduce(0.5f * p * sv[r]);      // v2'^T G' v2'
            n2  = sqrtf(pv);
            s2  = sqrtf(pp) / n2;
            d1b = d1;
            if (h == 0) {
                vecs[((size_t)b * 4 + 1) * ND + r] = sv[r];     // vb = v2'
                vecs[((size_t)b * 4 + 3) * ND + r] = p / nrm;   // v2 = v3'
            }
        }
        if (h == 0) sv[r] = p / nrm;
        __syncthreads();
    }

    if (t == 0) {
        const float rr = 1.f / (sqrtf(s2) + 1e-5f);
        float* pb = pars + b * 8;
        pb[0] = 1.f / n1;             // inv_n1
        pb[1] = 1.f / n2;             // inv_n2
        pb[2] = s1 * d1b / n2;        // k21
        pb[3] = rr;
        pb[4] = sqrtf(s1) - s1 * rr;  // c1
        pb[5] = sqrtf(s2) - s2 * rr;  // c2
        pb[6] = s1;
        pb[7] = s2;
    }
}

// ---------------------------------------------------------------------------
// Kernel 3: fused output pass. y = X*r + (c1*u1) v1^T + (c2*u2) v2^T.
// Grid: 256 batches x 16 column-tiles of 64. Each thread holds 16 float4 of X
// in registers, builds column-dot partials for u1/u2, LDS-reduces, transforms
// registers in place and stores. One read + one write of the 256 MB tensor.
// ---------------------------------------------------------------------------
__global__ __launch_bounds__(256, 2) void k3_out(const float* __restrict__ x,
                                                 const float* __restrict__ vecs,
                                                 const float* __restrict__ pars,
                                                 float* __restrict__ y)
{
    __shared__ float sva[ND], svb[ND], sv1[ND], sv2[ND];
    __shared__ float spr1[16][64], spr2[16][64];
    __shared__ float sg1[64], sg2[64];
    __shared__ float spar[8];

    const int t  = threadIdx.x;
    const int b  = blockIdx.x >> 4;
    const int n0 = (blockIdx.x & 15) * 64;

    {
        const float* vb = vecs + (size_t)b * 4 * ND;
        sva[t] = vb[t];
        svb[t] = vb[ND + t];
        sv1[t] = vb[2 * ND + t];
        sv2[t] = vb[3 * ND + t];
        if (t < 8) spar[t] = pars[b * 8 + t];
    }

    const int c4 = t & 15;     // float4 column group within tile
    const int rg = t >> 4;     // row group 0..15
    const float* xb = x + (size_t)b * ND * NN + n0 + c4 * 4;

    f32x4 xr[16];
    #pragma unroll
    for (int k = 0; k < 16; ++k)
        xr[k] = *(const f32x4*)(xb + (size_t)(rg + 16 * k) * NN);

    __syncthreads();

    // column-dot partials: a1 = X^T va, a2 = X^T vb (this tile's columns)
    f32x4 a1 = {0.f, 0.f, 0.f, 0.f}, a2 = {0.f, 0.f, 0.f, 0.f};
    #pragma unroll
    for (int k = 0; k < 16; ++k) {
        const int row = rg + 16 * k;
        a1 += xr[k] * sva[row];
        a2 += xr[k] * svb[row];
    }
    *(f32x4*)&spr1[rg][c4 * 4] = a1;
    *(f32x4*)&spr2[rg][c4 * 4] = a2;
    __syncthreads();

    if (t < 64) {
        float u1 = 0.f, u2 = 0.f;
        #pragma unroll
        for (int g2 = 0; g2 < 16; ++g2) { u1 += spr1[g2][t]; u2 += spr2[g2][t]; }
        const float uu1 = u1 * spar[0];                 // a1 / n1
        const float uu2 = u2 * spar[1] - spar[2] * uu1; // a2/n2 - k21*u1
        sg1[t] = spar[4] * uu1;                         // c1*u1
        sg2[t] = spar[5] * uu2;                         // c2*u2
    }
    __syncthreads();

    const float rr = spar[3];
    const f32x4 g1 = *(const f32x4*)&sg1[c4 * 4];
    const f32x4 g2 = *(const f32x4*)&sg2[c4 * 4];
    float* yb = y + (size_t)b * ND * NN + n0 + c4 * 4;
    #pragma unroll
    for (int k = 0; k < 16; ++k) {
        const int row = rg + 16 * k;
        const f32x4 o = xr[k] * rr + g1 * sv1[row] + g2 * sv2[row];
        *(f32x4*)(yb + (size_t)row * NN) = o;
    }
}

// ---------------------------------------------------------------------------
extern "C" void kernel_launch(void* const* d_in, const int* in_sizes, int n_in,
                              void* d_out, int out_size, void* d_ws, size_t ws_size,
                              hipStream_t stream)
{
    const float* x = (const float*)d_in[0];
    const float* w = (const float*)d_in[1];
    float* out = (float*)d_out;

    // fp16 G (32 MB) staged in the first part of d_out (256 MB); k3 overwrites it
    // only after k2 has consumed it (stream-ordered).
    f16_t* G = (f16_t*)d_out;

    // small per-batch results in workspace (~1.03 MB)
    float* vecs = (float*)d_ws;                  // [NB][4][ND]
    float* pars = vecs + (size_t)NB * 4 * ND;    // [NB][8]

    k1_gram<<<dim3(NB), dim3(512), 0, stream>>>(x, G);
    k2_power<<<dim3(NB), dim3(512), 0, stream>>>(G, w, vecs, pars);
    k3_out<<<dim3(NB * 16), dim3(256), 0, stream>>>(x, vecs, pars, out);
}